// Round 1
// baseline (108.955 us; speedup 1.0000x reference)
//
#include <hip/hip_runtime.h>
#include <math.h>

#define NRES 1024
#define TM_EPS 1e-8f

// One block per batch, single HBM pass. Coords live in registers across the
// whole kernel (no LDS stash). Block-reduce 15 Kabsch sums -> thread 0 runs a
// fp32 QCP (char-poly Newton + single-row adjugate w/ fallback) -> broadcast
// A,t -> score.
// This revision targets VGPR pressure in the serial solve: K2/Bm/cand are no
// longer materialized (row-at-a-time with early exit), Newton 12->8. Peak live
// regs in solve ~75 vs ~130 before, under the 128-VGPR cap of (256,4).
__global__ __launch_bounds__(256, 4) void tm_fused(const float* __restrict__ pred,
                                                   const float* __restrict__ act,
                                                   float* __restrict__ out,
                                                   float scale, float inv_d02) {
    __shared__ float red[4][15];
    __shared__ float rotsh[12];
    __shared__ float red2[4];

    int b = blockIdx.x;
    int t = threadIdx.x;
    const float4* p4 = (const float4*)(pred + (size_t)b * NRES * 3);
    const float4* a4 = (const float4*)(act  + (size_t)b * NRES * 3);

    float4 pf0 = p4[3 * t + 0], pf1 = p4[3 * t + 1], pf2 = p4[3 * t + 2];
    float4 af0 = a4[3 * t + 0], af1 = a4[3 * t + 1], af2 = a4[3 * t + 2];

    float px[4] = {pf0.x, pf0.w, pf1.z, pf2.y};
    float py[4] = {pf0.y, pf1.x, pf1.w, pf2.z};
    float pz[4] = {pf0.z, pf1.y, pf2.x, pf2.w};
    float ax[4] = {af0.x, af0.w, af1.z, af2.y};
    float ay[4] = {af0.y, af1.x, af1.w, af2.z};
    float az[4] = {af0.z, af1.y, af2.x, af2.w};

    // ---- phase 1: 15 partial sums ----
    {
        float acc[15];
#pragma unroll
        for (int i = 0; i < 15; i++) acc[i] = 0.f;
#pragma unroll
        for (int r = 0; r < 4; r++) {
            acc[0] += px[r]; acc[1] += py[r]; acc[2] += pz[r];
            acc[3] += ax[r]; acc[4] += ay[r]; acc[5] += az[r];
            acc[6]  += ax[r] * px[r]; acc[7]  += ax[r] * py[r]; acc[8]  += ax[r] * pz[r];
            acc[9]  += ay[r] * px[r]; acc[10] += ay[r] * py[r]; acc[11] += ay[r] * pz[r];
            acc[12] += az[r] * px[r]; acc[13] += az[r] * py[r]; acc[14] += az[r] * pz[r];
        }
#pragma unroll
        for (int off = 32; off > 0; off >>= 1) {
#pragma unroll
            for (int i = 0; i < 15; i++) acc[i] += __shfl_down(acc[i], off);
        }
        int wave = t >> 6, lane = t & 63;
        if (lane == 0) {
#pragma unroll
            for (int i = 0; i < 15; i++) red[wave][i] = acc[i];
        }
    }
    __syncthreads();

    // ---- phase 2 (thread 0): fp32 QCP solve, register-lean ----
    if (t == 0) {
        float s[15];
#pragma unroll
        for (int i = 0; i < 15; i++) s[i] = red[0][i] + red[1][i] + red[2][i] + red[3][i];

        const float n = (float)NRES;
        float mp[3], mq[3];
#pragma unroll
        for (int i = 0; i < 3; i++) { mp[i] = s[i] / n; mq[i] = s[3 + i] / n; }
        float M[3][3];
#pragma unroll
        for (int i = 0; i < 3; i++)
#pragma unroll
            for (int j = 0; j < 3; j++)
                M[i][j] = s[6 + i * 3 + j] - n * mq[i] * mp[j];

        float Sxx = M[0][0], Sxy = M[0][1], Sxz = M[0][2];
        float Syx = M[1][0], Syy = M[1][1], Syz = M[1][2];
        float Szx = M[2][0], Szy = M[2][1], Szz = M[2][2];
        float K[4][4];
        K[0][0] = Sxx + Syy + Szz; K[0][1] = Syz - Szy;        K[0][2] = Szx - Sxz;         K[0][3] = Sxy - Syx;
        K[1][0] = K[0][1];         K[1][1] = Sxx - Syy - Szz;  K[1][2] = Sxy + Syx;         K[1][3] = Szx + Sxz;
        K[2][0] = K[0][2];         K[2][1] = K[1][2];          K[2][2] = -Sxx + Syy - Szz;  K[2][3] = Syz + Szy;
        K[3][0] = K[0][3];         K[3][1] = K[1][3];          K[3][2] = K[2][3];           K[3][3] = -Sxx - Syy + Szz;

        // Power sums with K^2 fused row-by-row (no K2[4][4] materialized).
        float p2 = 0.f, p3 = 0.f, p4s = 0.f;
#pragma unroll
        for (int i = 0; i < 4; i++) {
            float row[4];
#pragma unroll
            for (int j = 0; j < 4; j++) {
                float a = 0.f;
#pragma unroll
                for (int k = 0; k < 4; k++) a += K[i][k] * K[k][j];
                row[j] = a;
            }
#pragma unroll
            for (int j = 0; j < 4; j++) {
                p2  += K[i][j] * K[i][j];
                p3  += row[j] * K[i][j];
                p4s += row[j] * row[j];
            }
        }
        float e2 = -0.5f * p2;
        float e3 = p3 * (1.f / 3.f);
        float e4 = (0.5f * p2 * p2 - p4s) * 0.25f;

        // Newton on the quartic from lam0 = sqrt(p2) >= lam_max (monotone).
        float lam = sqrtf(p2);
#pragma unroll
        for (int it = 0; it < 8; it++) {
            float lam2 = lam * lam;
            float P  = lam2 * lam2 + e2 * lam2 - e3 * lam + e4;
            float Pp = 4.f * lam * lam2 + 2.f * e2 * lam - e3;
            lam -= P / Pp;
        }

        // Adjugate of B = K - lam*I, one row at a time with early exit.
        // Any non-degenerate row of adj(B) is parallel to the eigenvector;
        // row 0 (w-component) dominates unless the rotation is near 180 deg.
        float q0 = 0.f, q1 = 0.f, q2 = 0.f, q3 = 0.f, bestn = -1.f;
        float fro2 = p2 + 4.f * lam * lam;                 // ||B||_F^2 (tr K = 0)
        float thr  = 1e-6f * fro2 * fro2 * fro2;           // (1e-3 * ||B||^3)^2

        auto Bv = [&](int i, int j) -> float {
            return K[i][j] - ((i == j) ? lam : 0.f);
        };
        auto tryrow = [&](int r) {
            int rr[3]; int k = 0;
#pragma unroll
            for (int i = 0; i < 4; i++) if (i != r) rr[k++] = i;
            float c[4];
#pragma unroll
            for (int cI = 0; cI < 4; cI++) {
                int cc[3]; int m = 0;
#pragma unroll
                for (int j = 0; j < 4; j++) if (j != cI) cc[m++] = j;
                float d =
                    Bv(rr[0],cc[0]) * (Bv(rr[1],cc[1]) * Bv(rr[2],cc[2]) - Bv(rr[1],cc[2]) * Bv(rr[2],cc[1]))
                  - Bv(rr[0],cc[1]) * (Bv(rr[1],cc[0]) * Bv(rr[2],cc[2]) - Bv(rr[1],cc[2]) * Bv(rr[2],cc[0]))
                  + Bv(rr[0],cc[2]) * (Bv(rr[1],cc[0]) * Bv(rr[2],cc[1]) - Bv(rr[1],cc[1]) * Bv(rr[2],cc[0]));
                c[cI] = (((r + cI) & 1) ? -d : d);
            }
            float nn = c[0] * c[0] + c[1] * c[1] + c[2] * c[2] + c[3] * c[3];
            if (nn > bestn) { bestn = nn; q0 = c[0]; q1 = c[1]; q2 = c[2]; q3 = c[3]; }
        };
        tryrow(0);
        if (bestn < thr) tryrow(1);
        if (bestn < thr) tryrow(2);
        if (bestn < thr) tryrow(3);

        float w = q0, x = q1, y = q2, z = q3;
        float inrm = 1.f / sqrtf(w * w + x * x + y * y + z * z);
        w *= inrm; x *= inrm; y *= inrm; z *= inrm;

        float A[3][3];
        A[0][0] = 1.f - 2.f * (y * y + z * z); A[0][1] = 2.f * (x * y - w * z);       A[0][2] = 2.f * (x * z + w * y);
        A[1][0] = 2.f * (x * y + w * z);       A[1][1] = 1.f - 2.f * (x * x + z * z); A[1][2] = 2.f * (y * z - w * x);
        A[2][0] = 2.f * (x * z - w * y);       A[2][1] = 2.f * (y * z + w * x);       A[2][2] = 1.f - 2.f * (x * x + y * y);

#pragma unroll
        for (int i = 0; i < 3; i++)
#pragma unroll
            for (int j = 0; j < 3; j++) rotsh[i * 3 + j] = A[i][j];
#pragma unroll
        for (int i = 0; i < 3; i++)
            rotsh[9 + i] = mp[i] - (A[i][0] * mq[0] + A[i][1] * mq[1] + A[i][2] * mq[2]);
    }
    __syncthreads();

    // ---- phase 3: score from registers ----
    float A00 = rotsh[0], A01 = rotsh[1], A02 = rotsh[2];
    float A10 = rotsh[3], A11 = rotsh[4], A12 = rotsh[5];
    float A20 = rotsh[6], A21 = rotsh[7], A22 = rotsh[8];
    float t0 = rotsh[9], t1 = rotsh[10], t2 = rotsh[11];

    float sc = 0.f;
#pragma unroll
    for (int r = 0; r < 4; r++) {
        float dx = px[r] - (A00 * ax[r] + A01 * ay[r] + A02 * az[r]) - t0 + TM_EPS;
        float dy = py[r] - (A10 * ax[r] + A11 * ay[r] + A12 * az[r]) - t1 + TM_EPS;
        float dz = pz[r] - (A20 * ax[r] + A21 * ay[r] + A22 * az[r]) - t2 + TM_EPS;
        float d2 = dx * dx + dy * dy + dz * dz;
        sc += 1.0f / (1.0f + d2 * inv_d02);
    }
#pragma unroll
    for (int off = 32; off > 0; off >>= 1) sc += __shfl_down(sc, off);

    int wave = t >> 6, lane = t & 63;
    if (lane == 0) red2[wave] = sc;
    __syncthreads();
    if (t == 0) {
        float tot = red2[0] + red2[1] + red2[2] + red2[3];
        atomicAdd(out, -tot * scale);
    }
}

extern "C" void kernel_launch(void* const* d_in, const int* in_sizes, int n_in,
                              void* d_out, int out_size, void* d_ws, size_t ws_size,
                              hipStream_t stream) {
    const float* pred = (const float*)d_in[0];
    const float* act  = (const float*)d_in[1];
    float* out = (float*)d_out;
    int B = in_sizes[0] / (NRES * 3);

    hipMemsetAsync(d_out, 0, sizeof(float), stream);

    double d0 = 1.24 * cbrt((double)NRES - 15.0) - 1.8;
    float inv_d02 = (float)(1.0 / (d0 * d0));
    float scale = 1.0f / ((float)B * (float)NRES);
    tm_fused<<<B, 256, 0, stream>>>(pred, act, out, scale, inv_d02);
}